// Round 10
// baseline (250.948 us; speedup 1.0000x reference)
//
#include <hip/hip_runtime.h>

#define N1c 25000
#define N2c 5000
#define Dc 256
#define DOUTc 128
#define EPSc 1e-5f
#define NEGc 0.01f
#define CAPc 32            // bucket capacity; passing degree ~Poisson(3.2)

typedef __attribute__((ext_vector_type(8))) short short8;
typedef __attribute__((ext_vector_type(4))) float f32x4;

__device__ __forceinline__ ushort f2bf(float f) {
    unsigned u = __float_as_uint(f);
    u += 0x7fffu + ((u >> 16) & 1u);          // round-to-nearest-even
    return (ushort)(u >> 16);
}
__device__ __forceinline__ float bf2f(ushort u) {
    return __uint_as_float(((unsigned)u) << 16);
}
__device__ __forceinline__ unsigned pack2(float lo, float hi) {
    return ((unsigned)f2bf(lo)) | (((unsigned)f2bf(hi)) << 16);
}
__device__ __forceinline__ int imin(int a, int b) { return a < b ? a : b; }

// ---- prep_fill: coalesced W transpose + single-pass bucketed CSR + mask1 ---
__global__ __launch_bounds__(256) void prep_fill(
    const int* __restrict__ src0, const int* __restrict__ dst0, const int* __restrict__ val0,
    const int* __restrict__ src1, const int* __restrict__ dst1, const int* __restrict__ val1,
    const int* __restrict__ ts, const int* __restrict__ time_p, const int* __restrict__ itv_p,
    const float* __restrict__ W1l, const float* __restrict__ W1r,
    const float* __restrict__ W2l, const float* __restrict__ W2r,
    int E0, int E1,
    ushort* __restrict__ Bt1, ushort* __restrict__ Bt2,
    int* __restrict__ cnt0, int* __restrict__ cnt1,
    int* __restrict__ eidx0, int* __restrict__ eidx1,
    float* __restrict__ mask_out) {
    const int flat = blockIdx.x * blockDim.x + threadIdx.x;
    const int NT = gridDim.x * blockDim.x;
    const int t0 = *time_p, iv = *itv_p;

    // ---- W transposes: 128 tiles (layer1) + 64 tiles (layer2), LDS 32x32 ---
    __shared__ float tl[32][33];
    const int tx = threadIdx.x & 31, ty = threadIdx.x >> 5;   // 32 x 8
    for (int t = blockIdx.x; t < 192; t += gridDim.x) {
        const bool L1 = t < 128;
        const int tt = L1 ? t : t - 128;
        const int ntn = L1 ? 8 : 4;
        const int kt = tt / ntn, nt = tt % ntn;
        const int k0 = kt * 32, n0 = nt * 32;
        const float* Wl = L1 ? W1l : W2l;
        const float* Wr = L1 ? W1r : W2r;
        const int nst = L1 ? 256 : 128;
        ushort* Bt = L1 ? Bt1 : Bt2;
#pragma unroll
        for (int rr = 0; rr < 4; ++rr) {          // read coalesced rows
            int r = ty * 4 + rr;
            int k = k0 + r;
            tl[r][tx] = (k < 256) ? Wl[(size_t)k * nst + n0 + tx]
                                  : Wr[(size_t)(k - 256) * nst + n0 + tx];
        }
        __syncthreads();
#pragma unroll
        for (int rr = 0; rr < 4; ++rr) {          // write coalesced k-runs
            int r = ty * 4 + rr;
            Bt[(size_t)(n0 + r) * 512 + k0 + tx] = f2bf(tl[tx][r]);
        }
        __syncthreads();
    }

    for (int e = flat; e < E0; e += NT) {
        int t = ts[val0[e]];
        if (t >= t0 && t < t0 + iv) {
            int d = dst0[e];
            int pos = atomicAdd(&cnt0[d], 1);
            if (pos < CAPc) eidx0[d * CAPc + pos] = src0[e];
        }
    }
    for (int e = flat; e < E1; e += NT) {
        int t = ts[val1[e]];
        bool m = (t >= t0 && t < t0 + iv);
        mask_out[e] = m ? 1.0f : 0.0f;
        if (m) {
            int d = dst1[e];
            int pos = atomicAdd(&cnt1[d], 1);
            if (pos < CAPc) eidx1[d * CAPc + pos] = src1[e];
        }
    }
}

// ---- gather + mean (fp32 x -> bf16 agg0), bucketed, one wave per row ------
// 25000 waves -> ~98 waves/CU queued: maximum TLP for the random-row reads.
__global__ void gather_f32(const float* __restrict__ X,
                           const int* __restrict__ cnt,
                           const int* __restrict__ eidx,
                           const int* __restrict__ src, const int* __restrict__ dst,
                           const int* __restrict__ val, const int* __restrict__ ts,
                           const int* __restrict__ time_p, const int* __restrict__ itv_p,
                           int E,
                           ushort* __restrict__ agg, int n) {
    int wave = (blockIdx.x * blockDim.x + threadIdx.x) >> 6;
    int lane = threadIdx.x & 63;
    if (wave >= n) return;
    int c = cnt[wave];
    int my = (lane < CAPc) ? eidx[wave * CAPc + lane] : 0;
    my = (lane < c) ? my : 0;
    float4 acc = make_float4(0.f, 0.f, 0.f, 0.f);
    float4 acc2 = make_float4(0.f, 0.f, 0.f, 0.f);
    if (c <= CAPc) {
        int j = 0;
        for (; j + 1 < c; j += 2) {
            int s0 = __shfl(my, j, 64);
            int s1 = __shfl(my, j + 1, 64);
            float4 v0 = *(const float4*)(X + (size_t)s0 * Dc + lane * 4);
            float4 v1 = *(const float4*)(X + (size_t)s1 * Dc + lane * 4);
            acc.x += v0.x; acc.y += v0.y; acc.z += v0.z; acc.w += v0.w;
            acc2.x += v1.x; acc2.y += v1.y; acc2.z += v1.z; acc2.w += v1.w;
        }
        if (j < c) {
            int s0 = __shfl(my, j, 64);
            float4 v0 = *(const float4*)(X + (size_t)s0 * Dc + lane * 4);
            acc.x += v0.x; acc.y += v0.y; acc.z += v0.z; acc.w += v0.w;
        }
    } else {
        // overflow fallback (statistically never taken; keeps any input correct)
        int t0 = *time_p, iv = *itv_p;
        for (int e = 0; e < E; ++e) {
            if (dst[e] != wave) continue;
            int t = ts[val[e]];
            if (t >= t0 && t < t0 + iv) {
                float4 v = *(const float4*)(X + (size_t)src[e] * Dc + lane * 4);
                acc.x += v.x; acc.y += v.y; acc.z += v.z; acc.w += v.w;
            }
        }
    }
    acc.x += acc2.x; acc.y += acc2.y; acc.z += acc2.z; acc.w += acc2.w;
    float inv = 1.0f / fmaxf((float)c, 1.0f);
    ushort4 o;
    o.x = f2bf(acc.x * inv); o.y = f2bf(acc.y * inv);
    o.z = f2bf(acc.z * inv); o.w = f2bf(acc.w * inv);
    *(ushort4*)(agg + (size_t)wave * Dc + lane * 4) = o;
}

// ---- gather + mean (bf16 h -> bf16 agg1), bucketed, one wave per row ------
__global__ void gather_bf16(const ushort* __restrict__ H,
                            const int* __restrict__ cnt,
                            const int* __restrict__ eidx,
                            const int* __restrict__ src, const int* __restrict__ dst,
                            const int* __restrict__ val, const int* __restrict__ ts,
                            const int* __restrict__ time_p, const int* __restrict__ itv_p,
                            int E,
                            ushort* __restrict__ agg, int n) {
    int wave = (blockIdx.x * blockDim.x + threadIdx.x) >> 6;
    int lane = threadIdx.x & 63;
    if (wave >= n) return;
    int c = cnt[wave];
    int my = (lane < CAPc) ? eidx[wave * CAPc + lane] : 0;
    my = (lane < c) ? my : 0;
    float4 acc = make_float4(0.f, 0.f, 0.f, 0.f);
    float4 acc2 = make_float4(0.f, 0.f, 0.f, 0.f);
    if (c <= CAPc) {
        int j = 0;
        for (; j + 1 < c; j += 2) {
            int s0 = __shfl(my, j, 64);
            int s1 = __shfl(my, j + 1, 64);
            ushort4 v0 = *(const ushort4*)(H + (size_t)s0 * Dc + lane * 4);
            ushort4 v1 = *(const ushort4*)(H + (size_t)s1 * Dc + lane * 4);
            acc.x += bf2f(v0.x); acc.y += bf2f(v0.y);
            acc.z += bf2f(v0.z); acc.w += bf2f(v0.w);
            acc2.x += bf2f(v1.x); acc2.y += bf2f(v1.y);
            acc2.z += bf2f(v1.z); acc2.w += bf2f(v1.w);
        }
        if (j < c) {
            int s0 = __shfl(my, j, 64);
            ushort4 v0 = *(const ushort4*)(H + (size_t)s0 * Dc + lane * 4);
            acc.x += bf2f(v0.x); acc.y += bf2f(v0.y);
            acc.z += bf2f(v0.z); acc.w += bf2f(v0.w);
        }
    } else {
        int t0 = *time_p, iv = *itv_p;
        for (int e = 0; e < E; ++e) {
            if (dst[e] != wave) continue;
            int t = ts[val[e]];
            if (t >= t0 && t < t0 + iv) {
                ushort4 v = *(const ushort4*)(H + (size_t)src[e] * Dc + lane * 4);
                acc.x += bf2f(v.x); acc.y += bf2f(v.y);
                acc.z += bf2f(v.z); acc.w += bf2f(v.w);
            }
        }
    }
    acc.x += acc2.x; acc.y += acc2.y; acc.z += acc2.z; acc.w += acc2.w;
    float inv = 1.0f / fmaxf((float)c, 1.0f);
    ushort4 o;
    o.x = f2bf(acc.x * inv); o.y = f2bf(acc.y * inv);
    o.z = f2bf(acc.z * inv); o.w = f2bf(acc.w * inv);
    *(ushort4*)(agg + (size_t)wave * Dc + lane * 4) = o;
}

// ---------------- bf16 MFMA GEMM: C = [Alo|A2] @ Bt^T + bias [,BN+leaky] ----
// K = 512 (two 256-halves). Bt [N][512] n-major. Block = 128 thr (2 waves),
// tile BM=32*GRPS x 128, BK=32.  (Proven correct in R1.)
// VARIANT 0 (GRPS=2): A2 = fp32 x (converted in staging), out bf16 h + BN.
// VARIANT 1 (GRPS=1): A2 = bf16 h, out fp32 + bias.
template <int VARIANT, int GRPS>
__global__ __launch_bounds__(128) void gemm_mfma(
    const ushort* __restrict__ Alo,
    const ushort* __restrict__ A2b, const float* __restrict__ A2f,
    const ushort* __restrict__ Bt,
    const float* __restrict__ bias,
    const float* __restrict__ g, const float* __restrict__ bt,
    const float* __restrict__ rm, const float* __restrict__ rv,
    void* __restrict__ Cout, int M) {
    constexpr int BM = 32 * GRPS;         // 64 or 32
    constexpr int TPR = 128 / BM;         // threads per row: 2 or 4
    constexpr int CHUNK = 32 / TPR;       // bf16 per thread: 16 or 8
    __shared__ ushort As[BM][40];         // +8 pad
    __shared__ ushort Bs[128][40];
    int tid = threadIdx.x;
    int wave = tid >> 6, lane = tid & 63;
    int quad = lane >> 4, l16 = lane & 15;
    int m0 = blockIdx.y * BM, n0 = blockIdx.x * 128;
    f32x4 acc[GRPS][8] = {};
    int ar = tid / TPR;
    int ak = (tid % TPR) * CHUNK;
    int bn = tid;
    for (int k0 = 0; k0 < 512; k0 += 32) {
        uint4 a0 = make_uint4(0, 0, 0, 0), a1 = make_uint4(0, 0, 0, 0);
        bool inb = (m0 + ar) < M;
        if (k0 < 256) {
            if (inb) {
                const ushort* Ag = Alo + (size_t)(m0 + ar) * Dc + k0 + ak;
                a0 = *(const uint4*)Ag;
                if (CHUNK == 16) a1 = *(const uint4*)(Ag + 8);
            }
        } else if (VARIANT == 0) {        // fp32 x -> bf16 in-register
            if (inb) {
                const float* Af = A2f + (size_t)(m0 + ar) * Dc + (k0 - 256) + ak;
                float4 f0 = *(const float4*)(Af + 0);
                float4 f1 = *(const float4*)(Af + 4);
                a0 = make_uint4(pack2(f0.x, f0.y), pack2(f0.z, f0.w),
                                pack2(f1.x, f1.y), pack2(f1.z, f1.w));
                if (CHUNK == 16) {
                    float4 f2 = *(const float4*)(Af + 8);
                    float4 f3 = *(const float4*)(Af + 12);
                    a1 = make_uint4(pack2(f2.x, f2.y), pack2(f2.z, f2.w),
                                    pack2(f3.x, f3.y), pack2(f3.z, f3.w));
                }
            }
        } else {
            if (inb) {
                const ushort* Ag = A2b + (size_t)(m0 + ar) * Dc + (k0 - 256) + ak;
                a0 = *(const uint4*)Ag;
                if (CHUNK == 16) a1 = *(const uint4*)(Ag + 8);
            }
        }
        const ushort* Bg = Bt + (size_t)(n0 + bn) * 512 + k0;
        uint4 b0 = *(const uint4*)(Bg + 0);
        uint4 b1 = *(const uint4*)(Bg + 8);
        uint4 b2 = *(const uint4*)(Bg + 16);
        uint4 b3 = *(const uint4*)(Bg + 24);
        __syncthreads();                  // prior iter's LDS reads done
        *(uint4*)&As[ar][ak] = a0;
        if (CHUNK == 16) *(uint4*)&As[ar][ak + 8] = a1;
        *(uint4*)&Bs[bn][0] = b0;
        *(uint4*)&Bs[bn][8] = b1;
        *(uint4*)&Bs[bn][16] = b2;
        *(uint4*)&Bs[bn][24] = b3;
        __syncthreads();
        short8 af[GRPS];
#pragma unroll
        for (int grp = 0; grp < GRPS; ++grp)
            af[grp] = *(const short8*)&As[wave * 16 * GRPS + grp * 16 + l16][quad * 8];
#pragma unroll
        for (int j = 0; j < 8; ++j) {
            short8 bf = *(const short8*)&Bs[j * 16 + l16][quad * 8];
#pragma unroll
            for (int grp = 0; grp < GRPS; ++grp)
                acc[grp][j] = __builtin_amdgcn_mfma_f32_16x16x32_bf16(af[grp], bf, acc[grp][j], 0, 0, 0);
        }
    }
    // epilogue: C/D layout col=lane&15, row=quad*4+reg
#pragma unroll
    for (int grp = 0; grp < GRPS; ++grp) {
#pragma unroll
        for (int j = 0; j < 8; ++j) {
            int gn = n0 + j * 16 + l16;
            float sc = 1.f, sh = bias[gn];
            if (VARIANT == 0) {
                float s = g[gn] * rsqrtf(rv[gn] + EPSc);
                sh = (bias[gn] - rm[gn]) * s + bt[gn];
                sc = s;
            }
            int gmb = m0 + wave * 16 * GRPS + grp * 16 + quad * 4;
#pragma unroll
            for (int r = 0; r < 4; ++r) {
                int gm = gmb + r;
                if (gm >= M) continue;
                float v = acc[grp][j][r];
                if (VARIANT == 0) {
                    v = v * sc + sh;
                    v = v >= 0.f ? v : NEGc * v;
                    ((ushort*)Cout)[(size_t)gm * Dc + gn] = f2bf(v);
                } else {
                    ((float*)Cout)[(size_t)gm * DOUTc + gn] = v + sh;
                }
            }
        }
    }
}

extern "C" void kernel_launch(void* const* d_in, const int* in_sizes, int n_in,
                              void* d_out, int out_size, void* d_ws, size_t ws_size,
                              hipStream_t stream) {
    const float* x    = (const float*)d_in[0];
    const int* src0   = (const int*)d_in[1];
    const int* dst0   = (const int*)d_in[2];
    const int* val0   = (const int*)d_in[3];
    const int* src1   = (const int*)d_in[4];
    const int* dst1   = (const int*)d_in[5];
    const int* val1   = (const int*)d_in[6];
    const int* ts     = (const int*)d_in[7];
    const int* time_p = (const int*)d_in[8];
    const int* itv_p  = (const int*)d_in[9];
    const float* W1l  = (const float*)d_in[10];
    const float* W1r  = (const float*)d_in[11];
    const float* b1   = (const float*)d_in[12];
    const float* g1   = (const float*)d_in[13];
    const float* bt1  = (const float*)d_in[14];
    const float* rm1  = (const float*)d_in[15];
    const float* rv1  = (const float*)d_in[16];
    const float* W2l  = (const float*)d_in[17];
    const float* W2r  = (const float*)d_in[18];
    const float* b2   = (const float*)d_in[19];
    int E0 = in_sizes[1];
    int E1 = in_sizes[4];
    float* out = (float*)d_out;

    // ---- workspace layout ----
    ushort* agg0 = (ushort*)d_ws;                  // [N1][256] bf16
    ushort* h    = agg0 + (size_t)N1c * Dc;        // [N1][256] bf16
    ushort* agg1 = h    + (size_t)N1c * Dc;        // [N2][256] bf16
    ushort* Bt1  = agg1 + (size_t)N2c * Dc;        // [256][512]
    ushort* Bt2  = Bt1  + 256 * 512;               // [128][512]
    int* ip      = (int*)(Bt2 + 128 * 512);
    int* cnt0    = ip;             ip += N1c;      // -- zeroed (memset)
    int* cnt1    = ip;             ip += N2c;      // -- zeroed (memset)
    int* eidx0   = ip;             ip += N1c * CAPc;
    int* eidx1   = ip;             ip += N2c * CAPc;
    float* mask_tail = out + (size_t)N2c * DOUTc;

    hipMemsetAsync(cnt0, 0, (size_t)(N1c + N2c) * sizeof(int), stream);

    prep_fill<<<2048, 256, 0, stream>>>(
        src0, dst0, val0, src1, dst1, val1, ts, time_p, itv_p,
        W1l, W1r, W2l, W2r, E0, E1, Bt1, Bt2,
        cnt0, cnt1, eidx0, eidx1, mask_tail);
    gather_f32<<<(N1c + 3) / 4, 256, 0, stream>>>(
        x, cnt0, eidx0, src0, dst0, val0, ts, time_p, itv_p, E0, agg0, N1c);
    gemm_mfma<0, 2><<<dim3(2, (N1c + 63) / 64), 128, 0, stream>>>(
        agg0, nullptr, x, Bt1, b1, g1, bt1, rm1, rv1, h, N1c);
    gather_bf16<<<(N2c + 3) / 4, 256, 0, stream>>>(
        h, cnt1, eidx1, src1, dst1, val1, ts, time_p, itv_p, E1, agg1, N2c);
    gemm_mfma<1, 1><<<dim3(1, (N2c + 31) / 32), 128, 0, stream>>>(
        agg1, h, nullptr, Bt2, b2, nullptr, nullptr, nullptr, nullptr, out, N2c);
}